// Round 8
// baseline (316.348 us; speedup 1.0000x reference)
//
#include <hip/hip_runtime.h>

// ResLSTM: B=4096, T=512, H=32.  One wave64 = TWO batch elements.
//   half = lane>>5 selects the batch, j = lane&31 is the hidden unit;
//   lane (half,j) owns all four gate rows of unit j (i,f,g,o).
//
// History: R4 LDS h-broadcast 407->330. R5 waves_per_eu 330->316.
// R7 pins 341 (LDS floor at 4 waves/SIMD). R8/R9/R10 readlane/SGPR/DPP
// broadcasts all regressed. R11 2-batch/wave: 341->297. R12 v_dot2_f32_f16
// MAC: 297->248.5 (absmax 9.8e-4 passes). R13 pin-hoist: neutral.
// R14 trans 10->7 (common-denominator rcp fusion): 249->230. MATCHED the
// trans-occupancy model: wave64 v_exp/v_rcp each occupy ~25-30 cy of VALU
// issue. Budget/wave-step at R14: 442 busy = 210 trans + 128 dot2 + ~60
// other + ~100 idle. Trans is half the pipe.
// R15 (this round): ZERO EXP2 -- all-rational gate math.
//   sigma(a) = (1+tanh(a/2))/2; tanh(z) ~= z*n(z^2)/d(z^2), Pade(7,6)
//   135135-family, clamp |z|<=5.2 (err <= ~1e-4, checked at 3,4,4.8,5,5.2).
//   i,f,o weights prescaled by 0.5 (exact in f16 -- better than old *log2e
//   rounding); g and c-tanh at scale 1. Common-denominator fusion keeps
//   TWO rcp total:
//     c' = [(Df+Nf)c*Di*Dg + (Di+Ni)*Ng*Df] * rcp(Df*Di*Dg) * 0.5
//     h  = 0.5*(Do+No)*Nc * rcp(Do*Dc)
//   Trans 7 -> 2. Predicted busy 442 -> ~334 cy/wave-step; 230 -> 180-205 us.
//   absmax expected ~1.0-1.5e-3. PRE-COMMIT: if absmax fails, revert i/f/o
//   to exp2-sigmoid next round, keep tanh polys.

static constexpr int T_LEN = 512;
static constexpr int H = 32;

typedef _Float16 h2 __attribute__((ext_vector_type(2)));

// float bit-pattern -> packed f16 pair
__device__ __forceinline__ h2 bch(float f) { return __builtin_bit_cast(h2, f); }

// D = dot2(a, b) + c  : 2 f16 MACs, fp32 accumulate (v_dot2_f32_f16)
__device__ __forceinline__ float fd2(float wbits, h2 p, float acc) {
#if __has_builtin(__builtin_amdgcn_fdot2)
    return __builtin_amdgcn_fdot2(__builtin_bit_cast(h2, wbits), p, acc, false);
#else
    float d = acc;
    asm("v_dot2_f32_f16 %0, %1, %2, %0"
        : "+v"(d) : "v"(__builtin_bit_cast(h2, wbits)), "v"(p));
    return d;
#endif
}

// pack two fp32 (prescaled) weights into one f16-pair bit pattern
__device__ __forceinline__ float packw(float w0, float w1) {
    h2 p;
    p[0] = (_Float16)w0;
    p[1] = (_Float16)w1;
    return __builtin_bit_cast(float, p);
}

__global__ void
__attribute__((amdgpu_flat_work_group_size(256, 256), amdgpu_waves_per_eu(2, 2)))
reslstm_kernel(const float* __restrict__ x,
               const float* __restrict__ W_ih,
               const float* __restrict__ W_hh,
               const float* __restrict__ b_ih,
               const float* __restrict__ b_hh,
               const float* __restrict__ W_fc,
               const float* __restrict__ b_fc,
               float* __restrict__ out, int B)
{
    // h as f16: [wave][half][40] (pad 80 B -> halves' same-address broadcast
    // groups sit 20 banks apart; all four b128 reads conflict-free).
    __shared__ _Float16 hbufh[4][2][40];
    __shared__ float    xbuf[4][72];     // [wave][half*36 + j]: 32-step x chunk

    const int lane = threadIdx.x & 63;
    const int wv   = threadIdx.x >> 6;
    const int j    = lane & 31;          // hidden unit
    const int half = lane >> 5;          // which batch of the pair

    const int b0 = (blockIdx.x << 3) + (wv << 1);
    if (b0 >= B) return;                 // wave-uniform guard
    const int bb   = b0 + half;
    const int bsrc = (bb < B) ? bb : b0; // clamp loads; store is guarded

    // W_hh rows for unit j, all four gates, PRESCALED (i,f,o: *0.5 for the
    // sigma(a)=(1+tanh(a/2))/2 form -- exact in f16; g: *1.0) and packed to
    // f16 pairs -> 64 VGPRs total.
    float wi2[16], wf2[16], wg2[16], wo2[16];
    {
        const float* ri = W_hh + (j     ) * H;
        const float* rf = W_hh + (j + 32) * H;
        const float* rg = W_hh + (j + 64) * H;
        const float* ro = W_hh + (j + 96) * H;
        #pragma unroll
        for (int k = 0; k < 16; ++k) {
            wi2[k] = packw(ri[2*k] * 0.5f, ri[2*k+1] * 0.5f);
            wf2[k] = packw(rf[2*k] * 0.5f, rf[2*k+1] * 0.5f);
            wg2[k] = packw(rg[2*k],        rg[2*k+1]);
            wo2[k] = packw(ro[2*k] * 0.5f, ro[2*k+1] * 0.5f);
        }
    }

    // x-projection weights & biases: fp32, same prescale.
    float wihi = W_ih[j]      * 0.5f;
    float wihf = W_ih[j + 32] * 0.5f;
    float wihg = W_ih[j + 64];
    float wiho = W_ih[j + 96] * 0.5f;
    float bi  = (b_ih[j]      + b_hh[j])      * 0.5f;
    float bfv = (b_ih[j + 32] + b_hh[j + 32]) * 0.5f;
    float bgv = (b_ih[j + 64] + b_hh[j + 64]);
    float bov = (b_ih[j + 96] + b_hh[j + 96]) * 0.5f;

    float h = 0.0f, c = 0.0f;
    hbufh[wv][half][j] = (_Float16)0.0f;      // h0 = 0 (wave-synchronous)

    const float* xrow = x + (size_t)bsrc * T_LEN;
    const float4* hb = reinterpret_cast<const float4*>(&hbufh[wv][half][0]);
    const float4* xb = reinterpret_cast<const float4*>(&xbuf[wv][half * 36]);

// Volatile pins (R6/R7 lesson): outputs feed the next tc iteration;
// reloading pinned values from memory is illegal -> weights stay
// VGPR-resident. Once per 32 steps (R13: per-step vs per-tc is neutral).
#define PIN16(P)                                                              \
    asm volatile("" : "+v"((P)[0]),  "+v"((P)[1]),  "+v"((P)[2]),  "+v"((P)[3]), \
                      "+v"((P)[4]),  "+v"((P)[5]),  "+v"((P)[6]),  "+v"((P)[7]), \
                      "+v"((P)[8]),  "+v"((P)[9]),  "+v"((P)[10]), "+v"((P)[11]),\
                      "+v"((P)[12]), "+v"((P)[13]), "+v"((P)[14]), "+v"((P)[15]))
#define PINALL()                                                              \
    PIN16(wi2); PIN16(wf2); PIN16(wg2); PIN16(wo2);                           \
    asm volatile("" : "+v"(wihi), "+v"(wihf), "+v"(wihg), "+v"(wiho),         \
                      "+v"(bi), "+v"(bfv), "+v"(bgv), "+v"(bov))

// 16 dot2 against one broadcast float4 (= 8 f16 = 4 h-pairs).
// Pairs M+0,M+2 -> chain1; M+1,M+3 -> chain2.
#define MACQ(HQ, M)                                                           \
    {   const h2 p0 = bch(HQ.x), p1 = bch(HQ.y),                              \
                 p2 = bch(HQ.z), p3 = bch(HQ.w);                              \
        a1i = fd2(wi2[M+0], p0, a1i); a1f = fd2(wf2[M+0], p0, a1f);           \
        a1g = fd2(wg2[M+0], p0, a1g); a1o = fd2(wo2[M+0], p0, a1o);           \
        a2i = fd2(wi2[M+1], p1, a2i); a2f = fd2(wf2[M+1], p1, a2f);           \
        a2g = fd2(wg2[M+1], p1, a2g); a2o = fd2(wo2[M+1], p1, a2o);           \
        a1i = fd2(wi2[M+2], p2, a1i); a1f = fd2(wf2[M+2], p2, a1f);           \
        a1g = fd2(wg2[M+2], p2, a1g); a1o = fd2(wo2[M+2], p2, a1o);           \
        a2i = fd2(wi2[M+3], p3, a2i); a2f = fd2(wf2[M+3], p3, a2f);           \
        a2g = fd2(wg2[M+3], p3, a2g); a2o = fd2(wo2[M+3], p3, a2o);           \
    }

// tanh(z) ~= zc*n(zc^2)/d(zc^2), zc=clamp(z,+-5.2). Pade(7,6) 135135-family
// normalized: n = 1 + s*(C1N + s*(C2N + s*C3N)), d likewise. err <= ~1e-4.
#define TPOLY(Z, NN, DD) do {                                                 \
    const float zc = __builtin_fminf(__builtin_fmaxf((Z), -5.2f), 5.2f);      \
    const float s_ = zc * zc;                                                 \
    DD = __builtin_fmaf(__builtin_fmaf(__builtin_fmaf(                        \
             2.0719799e-4f, s_, 0.023309676f), s_, 0.46153846f), s_, 1.0f);   \
    NN = zc * __builtin_fmaf(__builtin_fmaf(__builtin_fmaf(                   \
             7.3999408e-6f, s_, 0.0027972028f), s_, 0.12820513f), s_, 1.0f);  \
} while (0)

// R15 gate math (zero exp2):
//   sigma gates (i,f,o): acc is a/2; sigma = (D+N)/(2D).
//   g, tanh(c): T = N/D.
//   c' = [(Df+Nf)*c*(Di*Dg) + (Di+Ni)*(Ng*Df)] * rcp(Df*Di*Dg) * 0.5
//   h  = 0.5*(Do+No)*Nc * rcp(Do*Dc)
#define STEP(XT) do {                                                         \
    float a1i = __builtin_fmaf(XT, wihi, bi);                                 \
    float a1f = __builtin_fmaf(XT, wihf, bfv);                                \
    float a1g = __builtin_fmaf(XT, wihg, bgv);                                \
    float a1o = __builtin_fmaf(XT, wiho, bov);                                \
    float a2i = 0.0f, a2f = 0.0f, a2g = 0.0f, a2o = 0.0f;                     \
    {   /* h(t-1) broadcast: 4x same-address b128 per half (32 f16) */        \
        const float4 h0 = hb[0], h1 = hb[1], h2q = hb[2], h3 = hb[3];         \
        MACQ(h0, 0) MACQ(h1, 4) MACQ(h2q, 8) MACQ(h3, 12)                     \
    }                                                                         \
    const float ai = a1i + a2i, af_ = a1f + a2f;                              \
    const float ag = a1g + a2g, ao  = a1o + a2o;                              \
    float Ni_, Di_, Nf_, Df_, Ng_, Dg_, No_, Do_;                             \
    TPOLY(ai,  Ni_, Di_);                                                     \
    TPOLY(af_, Nf_, Df_);                                                     \
    TPOLY(ag,  Ng_, Dg_);                                                     \
    TPOLY(ao,  No_, Do_);                                                     \
    const float P_  = Di_ * Dg_;                                              \
    const float A_  = (Df_ + Nf_) * c;                                        \
    const float B_  = (Di_ + Ni_) * (Ng_ * Df_);                              \
    const float U_  = __builtin_fmaf(A_, P_, B_);                             \
    const float Rc_ = __builtin_amdgcn_rcpf(Df_ * P_);                        \
    c = (0.5f * U_) * Rc_;                                                    \
    float Nc_, Dc_;                                                           \
    TPOLY(c, Nc_, Dc_);                                                       \
    const float Rh_ = __builtin_amdgcn_rcpf(Do_ * Dc_);                       \
    h = (0.5f * ((Do_ + No_) * Nc_)) * Rh_;                                   \
    hbufh[wv][half][j] = (_Float16)h;        /* publish for next step */      \
} while (0)

    float xcur = xrow[j];                     // chunk 0 of this half's batch
    for (int tc = 0; tc < T_LEN / 32; ++tc) {
        PINALL();                             // once per 32 steps
        xbuf[wv][half * 36 + j] = xcur;       // stage 32 steps of x
        float xnext = 0.0f;
        if (tc + 1 < T_LEN / 32) xnext = xrow[(tc + 1) * 32 + j];  // prefetch
        for (int t4 = 0; t4 < 8; ++t4) {
            const float4 xq = xb[t4];         // 4 steps of x, broadcast/half
            STEP(xq.x); STEP(xq.y); STEP(xq.z); STEP(xq.w);
        }
        xcur = xnext;
    }
#undef STEP
#undef TPOLY
#undef MACQ
#undef PINALL
#undef PIN16

    // out[bb] = sum_j h[j]*W_fc[j] + b_fc  (butterfly within each half)
    float val = h * W_fc[j];
    #pragma unroll
    for (int off = 16; off >= 1; off >>= 1)
        val += __shfl_xor(val, off);
    if (j == 0 && bb < B) out[bb] = val + b_fc[0];
}

extern "C" void kernel_launch(void* const* d_in, const int* in_sizes, int n_in,
                              void* d_out, int out_size, void* d_ws, size_t ws_size,
                              hipStream_t stream) {
    const float* x    = (const float*)d_in[0];
    const float* W_ih = (const float*)d_in[1];
    const float* W_hh = (const float*)d_in[2];
    const float* b_ih = (const float*)d_in[3];
    const float* b_hh = (const float*)d_in[4];
    const float* W_fc = (const float*)d_in[5];
    const float* b_fc = (const float*)d_in[6];
    float* out = (float*)d_out;
    const int B = in_sizes[0] / T_LEN;        // 4096
    dim3 block(256);                          // 4 waves = 8 batch elements
    dim3 grid((B + 7) / 8);                   // 512 blocks -> 2 waves/SIMD
    reslstm_kernel<<<grid, block, 0, stream>>>(x, W_ih, W_hh, b_ih, b_hh,
                                               W_fc, b_fc, out, B);
}

// Round 9
// 258.272 us; speedup vs baseline: 1.2249x; 1.2249x over previous
//
#include <hip/hip_runtime.h>

// ResLSTM: B=4096, T=512, H=32.
// R16 STRUCTURE: one wave64 = FOUR batch elements.
//   bg = lane>>4 (batch of the quad), li = lane&15. Lane owns units
//   {2li, 2li+1} x all four gates of batch bg -> 8 dot2-accumulators.
//   128 dot2/wave-step covers 4 batch-steps (32/batch, the dot2 floor);
//   xproj/gate/LDS/loop overhead amortized 2x vs R11/R14's 2-batch wave.
//   1024 waves -> 1 wave/SIMD (waves_per_eu(1,1), 512-VGPR budget;
//   weights = 128 f16-pair VGPRs).
//
// History: R4 330 (LDS broadcast) R5 316 R7 341 (pins; LDS-pipe floor at
// 4 waves/SIMD). R8/R9/R10 readlane/SGPR/DPP broadcasts all lost to LDS.
// R11 2-batch/wave 297. R12 dot2 f16 MAC 248.5 (absmax 9.8e-4 OK).
// R13 pin-hoist neutral. R14 rcp-fusion 230.
// R15 all-rational REGRESSED 291: polys (+100cy) >> exp2 saved => trans
// ops are CHEAP (~4-10cy issue, quarter-rate pipe); the 25-30cy model is
// dead. Cost model now: pure instruction count, dot2 block dominant.
// R14 ledger: 539 cy wall/wave-step, 416 cy/SIMD issue demand (77% eff).
// R16 predict: ~390 cy issue + ~150 exposed latency per wave-step for
// 4 batches -> 115-170 us. Failure (>=210, VALUBusy<60): latency exposure
// at 1 wave/SIMD -> revert R14, overlap h-roundtrip instead.

static constexpr int T_LEN = 512;
static constexpr int H = 32;

typedef _Float16 h2 __attribute__((ext_vector_type(2)));

__device__ __forceinline__ h2 bch(float f) { return __builtin_bit_cast(h2, f); }

// D = dot2(a,b) + c : 2 f16 MACs, fp32 accumulate (v_dot2_f32_f16)
__device__ __forceinline__ float fd2(float wbits, h2 p, float acc) {
#if __has_builtin(__builtin_amdgcn_fdot2)
    return __builtin_amdgcn_fdot2(__builtin_bit_cast(h2, wbits), p, acc, false);
#else
    float d = acc;
    asm("v_dot2_f32_f16 %0, %1, %2, %0"
        : "+v"(d) : "v"(__builtin_bit_cast(h2, wbits)), "v"(p));
    return d;
#endif
}

__device__ __forceinline__ float packw(float a, float b) {
    h2 p; p[0] = (_Float16)a; p[1] = (_Float16)b;
    return __builtin_bit_cast(float, p);
}

__global__ void
__attribute__((amdgpu_flat_work_group_size(256, 256), amdgpu_waves_per_eu(1, 1)))
reslstm_kernel(const float* __restrict__ x,
               const float* __restrict__ W_ih,
               const float* __restrict__ W_hh,
               const float* __restrict__ b_ih,
               const float* __restrict__ b_hh,
               const float* __restrict__ W_fc,
               const float* __restrict__ b_fc,
               float* __restrict__ out, int B)
{
    // h as f16: [wave][batch][40] (pad 80 B -> the four per-batch broadcast
    // bases sit 20 banks apart; all b128 reads conflict-free).
    __shared__ _Float16 hb4[4][4][40];
    // x chunk: [wave][batch][36] (pad 36 floats = 9 banks -> disjoint spans).
    __shared__ float    xb4[4][4][36];

    const int lane = threadIdx.x & 63;
    const int wv   = threadIdx.x >> 6;
    const int bg   = lane >> 4;          // batch of the quad (0..3)
    const int li   = lane & 15;          // unit-pair index (0..15)
    const int u0   = li << 1;            // units u0, u0+1

    const int wbase = (blockIdx.x << 4) + (wv << 2);   // 16 batches/block
    if (wbase >= B) return;              // wave-uniform guard
    const int bb   = wbase + bg;
    const int bsrc = (bb < B) ? bb : 0;  // clamp loads; store is guarded

    constexpr float NL2E  = -1.4426950408889634f;   // -log2(e)
    constexpr float N2L2E = 2.0f * NL2E;

    // W_hh rows for units u0,u0+1, all four gates, PRESCALED (i,f,o: *NL2E;
    // g: *2NL2E), packed f16 pairs -> 128 VGPRs. wgt[g][s][k]: gate g
    // (0=i,1=f,2=g,3=o), unit u0+s, h-pair k (units 2k,2k+1).
    float wgt[4][2][16];
    #pragma unroll
    for (int g = 0; g < 4; ++g) {
        const float sc = (g == 2) ? N2L2E : NL2E;
        #pragma unroll
        for (int s = 0; s < 2; ++s) {
            const float4* pr =
                reinterpret_cast<const float4*>(W_hh + (g * 32 + u0 + s) * H);
            #pragma unroll
            for (int kk = 0; kk < 8; ++kk) {
                const float4 q = pr[kk];
                wgt[g][s][2*kk]   = packw(q.x * sc, q.y * sc);
                wgt[g][s][2*kk+1] = packw(q.z * sc, q.w * sc);
            }
        }
    }
    // x-projection weights & fused biases (same prescale), fp32.
    float wih[4][2], bsb[4][2];
    #pragma unroll
    for (int g = 0; g < 4; ++g) {
        const float sc = (g == 2) ? N2L2E : NL2E;
        #pragma unroll
        for (int s = 0; s < 2; ++s) {
            const int r = g * 32 + u0 + s;
            wih[g][s] = W_ih[r] * sc;
            bsb[g][s] = (b_ih[r] + b_hh[r]) * sc;
        }
    }

    float c0 = 0.0f, c1 = 0.0f, h0v = 0.0f, h1v = 0.0f;
    hb4[wv][bg][u0]     = (_Float16)0.0f;   // h0 = 0 (wave-synchronous)
    hb4[wv][bg][u0 + 1] = (_Float16)0.0f;

    const float* xrow = x + (size_t)bsrc * T_LEN;
    const float4* hq  = reinterpret_cast<const float4*>(&hb4[wv][bg][0]);
    const float4* xq4 = reinterpret_cast<const float4*>(&xb4[wv][bg][0]);

// Volatile pins (R6/R7 lesson): outputs feed the next tc iteration;
// reloading pinned values from memory is illegal -> weights stay
// VGPR-resident. Once per 32 steps (R13: placement is neutral).
#define PIN16(P)                                                              \
    asm volatile("" : "+v"((P)[0]),  "+v"((P)[1]),  "+v"((P)[2]),  "+v"((P)[3]), \
                      "+v"((P)[4]),  "+v"((P)[5]),  "+v"((P)[6]),  "+v"((P)[7]), \
                      "+v"((P)[8]),  "+v"((P)[9]),  "+v"((P)[10]), "+v"((P)[11]),\
                      "+v"((P)[12]), "+v"((P)[13]), "+v"((P)[14]), "+v"((P)[15]))
#define PINALL()                                                              \
    PIN16(wgt[0][0]); PIN16(wgt[0][1]); PIN16(wgt[1][0]); PIN16(wgt[1][1]);   \
    PIN16(wgt[2][0]); PIN16(wgt[2][1]); PIN16(wgt[3][0]); PIN16(wgt[3][1]);   \
    asm volatile("" : "+v"(wih[0][0]), "+v"(wih[0][1]), "+v"(wih[1][0]),      \
                      "+v"(wih[1][1]), "+v"(wih[2][0]), "+v"(wih[2][1]),      \
                      "+v"(wih[3][0]), "+v"(wih[3][1]),                       \
                      "+v"(bsb[0][0]), "+v"(bsb[0][1]), "+v"(bsb[1][0]),      \
                      "+v"(bsb[1][1]), "+v"(bsb[2][0]), "+v"(bsb[2][1]),      \
                      "+v"(bsb[3][0]), "+v"(bsb[3][1]))

// 32 dot2 against one broadcast float4 (8 f16 = 4 h-pairs) for 8 accums.
#define MACQ(HQ, M)                                                           \
    {   const h2 p0 = bch(HQ.x), p1 = bch(HQ.y),                              \
                 p2 = bch(HQ.z), p3 = bch(HQ.w);                              \
        ai0 = fd2(wgt[0][0][M+0], p0, ai0); af0 = fd2(wgt[1][0][M+0], p0, af0); \
        ag0 = fd2(wgt[2][0][M+0], p0, ag0); ao0 = fd2(wgt[3][0][M+0], p0, ao0); \
        ai1 = fd2(wgt[0][1][M+0], p0, ai1); af1 = fd2(wgt[1][1][M+0], p0, af1); \
        ag1 = fd2(wgt[2][1][M+0], p0, ag1); ao1 = fd2(wgt[3][1][M+0], p0, ao1); \
        ai0 = fd2(wgt[0][0][M+1], p1, ai0); af0 = fd2(wgt[1][0][M+1], p1, af0); \
        ag0 = fd2(wgt[2][0][M+1], p1, ag0); ao0 = fd2(wgt[3][0][M+1], p1, ao0); \
        ai1 = fd2(wgt[0][1][M+1], p1, ai1); af1 = fd2(wgt[1][1][M+1], p1, af1); \
        ag1 = fd2(wgt[2][1][M+1], p1, ag1); ao1 = fd2(wgt[3][1][M+1], p1, ao1); \
        ai0 = fd2(wgt[0][0][M+2], p2, ai0); af0 = fd2(wgt[1][0][M+2], p2, af0); \
        ag0 = fd2(wgt[2][0][M+2], p2, ag0); ao0 = fd2(wgt[3][0][M+2], p2, ao0); \
        ai1 = fd2(wgt[0][1][M+2], p2, ai1); af1 = fd2(wgt[1][1][M+2], p2, af1); \
        ag1 = fd2(wgt[2][1][M+2], p2, ag1); ao1 = fd2(wgt[3][1][M+2], p2, ao1); \
        ai0 = fd2(wgt[0][0][M+3], p3, ai0); af0 = fd2(wgt[1][0][M+3], p3, af0); \
        ag0 = fd2(wgt[2][0][M+3], p3, ag0); ao0 = fd2(wgt[3][0][M+3], p3, ao0); \
        ai1 = fd2(wgt[0][1][M+3], p3, ai1); af1 = fd2(wgt[1][1][M+3], p3, af1); \
        ag1 = fd2(wgt[2][1][M+3], p3, ag1); ao1 = fd2(wgt[3][1][M+3], p3, ao1); \
    }

// R14 exp2 gate math (R15 polys reverted). Accums pre-scaled by -log2(e):
//   c' = [c*Di*Dg + (1-Eg)*Df] * rcp(Df*Di*Dg);  h = (1-Ec) * rcp(Do*Dc).
#define GSTATE(AI, AF, AG, AO, CC, HH) do {                                   \
    const float Ei = __builtin_amdgcn_exp2f(AI);                              \
    const float Ef = __builtin_amdgcn_exp2f(AF);                              \
    const float Eg = __builtin_amdgcn_exp2f(AG);                              \
    const float Eo = __builtin_amdgcn_exp2f(AO);                              \
    const float Di = 1.0f + Ei, Df = 1.0f + Ef;                               \
    const float Dg = 1.0f + Eg, Do_ = 1.0f + Eo;                              \
    const float P  = Di * Dg;                                                 \
    const float t_ = (1.0f - Eg) * Df;                                        \
    const float u_ = __builtin_fmaf(CC, P, t_);                               \
    const float Rc = __builtin_amdgcn_rcpf(Df * P);                           \
    CC = u_ * Rc;                                                             \
    const float Ec = __builtin_amdgcn_exp2f(CC * N2L2E);                      \
    const float Dc = 1.0f + Ec;                                               \
    const float Rh = __builtin_amdgcn_rcpf(Do_ * Dc);                         \
    HH = (1.0f - Ec) * Rh;                                                    \
} while (0)

#define STEP(XT) do {                                                         \
    float ai0 = __builtin_fmaf(XT, wih[0][0], bsb[0][0]);                     \
    float af0 = __builtin_fmaf(XT, wih[1][0], bsb[1][0]);                     \
    float ag0 = __builtin_fmaf(XT, wih[2][0], bsb[2][0]);                     \
    float ao0 = __builtin_fmaf(XT, wih[3][0], bsb[3][0]);                     \
    float ai1 = __builtin_fmaf(XT, wih[0][1], bsb[0][1]);                     \
    float af1 = __builtin_fmaf(XT, wih[1][1], bsb[1][1]);                     \
    float ag1 = __builtin_fmaf(XT, wih[2][1], bsb[2][1]);                     \
    float ao1 = __builtin_fmaf(XT, wih[3][1], bsb[3][1]);                     \
    {   /* h(t-1) of batch bg: 4x b128, 16-lane same-address broadcast */     \
        const float4 hq0 = hq[0], hq1 = hq[1], hq2 = hq[2], hq3 = hq[3];      \
        MACQ(hq0, 0) MACQ(hq1, 4) MACQ(hq2, 8) MACQ(hq3, 12)                  \
    }                                                                         \
    GSTATE(ai0, af0, ag0, ao0, c0, h0v);                                      \
    GSTATE(ai1, af1, ag1, ao1, c1, h1v);                                      \
    h2 ph; ph[0] = (_Float16)h0v; ph[1] = (_Float16)h1v;                      \
    *reinterpret_cast<h2*>(&hb4[wv][bg][u0]) = ph;  /* publish 2 units */     \
} while (0)

    float2 xcur = *reinterpret_cast<const float2*>(xrow + (li << 1));
    for (int tc = 0; tc < T_LEN / 32; ++tc) {
        PINALL();                             // once per 32 steps
        // stage 32 steps of x for all 4 batches (each lane: 2 floats)
        *reinterpret_cast<float2*>(&xb4[wv][bg][li << 1]) = xcur;
        if (tc + 1 < T_LEN / 32)
            xcur = *reinterpret_cast<const float2*>(
                       xrow + (tc + 1) * 32 + (li << 1));   // prefetch
        for (int t4 = 0; t4 < 8; ++t4) {
            const float4 xv = xq4[t4];        // 4 steps of x, per-batch bcast
            STEP(xv.x); STEP(xv.y); STEP(xv.z); STEP(xv.w);
        }
    }
#undef STEP
#undef GSTATE
#undef MACQ
#undef PINALL
#undef PIN16

    // out[bb] = sum_j h[j]*W_fc[j] + b_fc  (reduce over the 16-lane group)
    float val = __builtin_fmaf(h0v, W_fc[u0], h1v * W_fc[u0 + 1]);
    #pragma unroll
    for (int off = 8; off >= 1; off >>= 1)
        val += __shfl_xor(val, off);
    if (li == 0 && bb < B) out[bb] = val + b_fc[0];
}

extern "C" void kernel_launch(void* const* d_in, const int* in_sizes, int n_in,
                              void* d_out, int out_size, void* d_ws, size_t ws_size,
                              hipStream_t stream) {
    const float* x    = (const float*)d_in[0];
    const float* W_ih = (const float*)d_in[1];
    const float* W_hh = (const float*)d_in[2];
    const float* b_ih = (const float*)d_in[3];
    const float* b_hh = (const float*)d_in[4];
    const float* W_fc = (const float*)d_in[5];
    const float* b_fc = (const float*)d_in[6];
    float* out = (float*)d_out;
    const int B = in_sizes[0] / T_LEN;        // 4096
    dim3 block(256);                          // 4 waves = 16 batch elements
    dim3 grid((B + 15) / 16);                 // 256 blocks -> 1 wave/SIMD
    reslstm_kernel<<<grid, block, 0, stream>>>(x, W_ih, W_hh, b_ih, b_hh,
                                               W_fc, b_fc, out, B);
}